// Round 6
// baseline (347.783 us; speedup 1.0000x reference)
//
#include <hip/hip_runtime.h>

#define TT 1024
#define KK 16
#define HH 20
#define NCELL 1024

__device__ __forceinline__ float fast_rcp(float x) {
    return __builtin_amdgcn_rcpf(x);
}
__device__ __forceinline__ float sigm(float x) {
    return fast_rcp(1.0f + __expf(-x));
}
__device__ __forceinline__ float tanh_fast(float x) {
    float e = __expf(2.0f * x);
    return 1.0f - 2.0f * fast_rcp(e + 1.0f);
}

__device__ __forceinline__ float bcast(float v, int srclane) {
    return __int_as_float(__builtin_amdgcn_readlane(__float_as_int(v), srclane));
}

struct F3 { float x, y, z; };

// ONE cell per wave: lanes 0..19 own hidden units (lane j = unit j's four gate
// rows, 80 weights held in VGPRs). Per-step h broadcast = 20 x v_readlane into
// SGPRs; the gate FMAs consume h directly as the one-allowed-SGPR operand of
// v_fma_f32 (no LDS pipe, no barriers, no pack movs).
//
// amdgpu_waves_per_eu(1): we run exactly 1 wave/SIMD (1024 blocks on 256 CUs).
// R4/R5 showed the default occupancy heuristic caps the allocation at 64 VGPRs
// (launch_bounds(64,1) was ignored), which forces the 80 per-lane weights to
// be reloaded from cache every step (~430 cy/step of stall). The function
// attribute sets the budget directly.
__global__ __launch_bounds__(64, 1)
__attribute__((amdgpu_waves_per_eu(1)))
void lstm_kernel(
    const float* __restrict__ inp,    // [B][T][K][3]
    const float* __restrict__ W_ih,   // [K][80][3]
    const float* __restrict__ W_hh,   // [K][80][20]
    const float* __restrict__ b_ih,   // [K][80]
    const float* __restrict__ b_hh,   // [K][80]
    const float* __restrict__ w,      // [K*B+1]
    const float* __restrict__ conv_w, // [21]
    const float* __restrict__ conv_b, // [1]
    float* __restrict__ y_ws)         // [1024] pre-softmax y for rows 1..1024
{
    const int lane = threadIdx.x;
    const int cell = blockIdx.x;           // 0..1023
    const int k = cell >> 6;
    const int b = cell & 63;
    const int j = (lane < HH) ? lane : (HH - 1);  // lanes 20..63 shadow unit 19

    // Per-lane weights in registers (80 VGPRs of W_hh + 12 of W_ih + 4 bias).
    float W0[HH], W1[HH], W2[HH], W3[HH];
    float Wi0[3], Wi1[3], Wi2[3], Wi3[3];
    float bias0, bias1, bias2, bias3;
    {
        const int r0 = k * 80 + 0 * HH + j;
        const int r1 = k * 80 + 1 * HH + j;
        const int r2 = k * 80 + 2 * HH + j;
        const int r3 = k * 80 + 3 * HH + j;
        #pragma unroll
        for (int hh = 0; hh < HH; ++hh) {
            W0[hh] = W_hh[r0 * HH + hh];
            W1[hh] = W_hh[r1 * HH + hh];
            W2[hh] = W_hh[r2 * HH + hh];
            W3[hh] = W_hh[r3 * HH + hh];
        }
        #pragma unroll
        for (int i = 0; i < 3; ++i) {
            Wi0[i] = W_ih[r0 * 3 + i];
            Wi1[i] = W_ih[r1 * 3 + i];
            Wi2[i] = W_ih[r2 * 3 + i];
            Wi3[i] = W_ih[r3 * 3 + i];
        }
        bias0 = b_ih[r0] + b_hh[r0];
        bias1 = b_ih[r1] + b_hh[r1];
        bias2 = b_ih[r2] + b_hh[r2];
        bias3 = b_ih[r3] + b_hh[r3];
    }

    float h_own = 0.0f, c_own = 0.0f;

    // Wave-uniform input base: inp[((b*T + t)*K + k)*3], stride 48 floats/t.
    const float* xb = inp + (b * TT * KK + k) * 3;
    F3 p0{xb[0 * 48], xb[0 * 48 + 1], xb[0 * 48 + 2]};
    F3 p1{xb[1 * 48], xb[1 * 48 + 1], xb[1 * 48 + 2]};
    F3 p2{xb[2 * 48], xb[2 * 48 + 1], xb[2 * 48 + 2]};
    F3 p3{xb[3 * 48], xb[3 * 48 + 1], xb[3 * 48 + 2]};

    auto step = [&](F3& p, int t) {
        // 1) h broadcast: 20 readlanes -> SGPRs (no LDS pipe, no movs)
        float hs[HH];
        #pragma unroll
        for (int hh = 0; hh < HH; ++hh) hs[hh] = bcast(h_own, hh);

        const float x0 = p.x, x1 = p.y, x2 = p.z;
        // 2) refill p for step t+4 (uniform address; latency spans 4 steps)
        {
            int tn = t + 4; tn = (tn < TT) ? tn : (TT - 1);
            const float* q = xb + tn * (KK * 3);
            p.x = q[0]; p.y = q[1]; p.z = q[2];
        }
        // 3) x-projection + bias
        float a0 = bias0 + Wi0[0] * x0 + Wi0[1] * x1 + Wi0[2] * x2;
        float a1 = bias1 + Wi1[0] * x0 + Wi1[1] * x1 + Wi1[2] * x2;
        float a2 = bias2 + Wi2[0] * x0 + Wi2[1] * x1 + Wi2[2] * x2;
        float a3 = bias3 + Wi3[0] * x0 + Wi3[1] * x1 + Wi3[2] * x2;
        // 4) gate dots: v_fma with SGPR h operand, 4 independent chains
        #pragma unroll
        for (int hh = 0; hh < HH; ++hh) {
            const float hv = hs[hh];
            a0 += W0[hh] * hv;
            a1 += W1[hh] * hv;
            a2 += W2[hh] * hv;
            a3 += W3[hh] * hv;
        }
        // 5) nonlinearity + state update
        const float ig = sigm(a0);
        const float fg = sigm(a1);
        const float gt = tanh_fast(a2);
        const float og = sigm(a3);
        c_own = fg * c_own + ig * gt;
        h_own = og * tanh_fast(c_own);
    };

    for (int tb = 0; tb < TT; tb += 4) {
        step(p0, tb + 0);
        step(p1, tb + 1);
        step(p2, tb + 2);
        step(p3, tb + 3);
    }

    // Epilogue: final h via readlane (uniform), y = tanh(feat . conv_w + conv_b)
    float acc = conv_b[0];
    #pragma unroll
    for (int hh = 0; hh < HH; ++hh) acc += conv_w[hh] * bcast(h_own, hh);
    acc += conv_w[HH] * w[1 + cell];
    if (lane == 0) y_ws[cell] = tanh_fast(acc);
}

// Softmax over [1, y_0 .. y_1023] -> out[1025]
__global__ __launch_bounds__(256) void softmax_kernel(
    const float* __restrict__ y_ws, float* __restrict__ out)
{
    __shared__ float red[4];
    const int tid = threadIdx.x;
    float vals[5];
    float local = 0.0f;
    #pragma unroll
    for (int it = 0; it < 5; ++it) {
        const int idx = tid + it * 256;
        if (idx < NCELL + 1) {
            const float y = (idx == 0) ? 1.0f : y_ws[idx - 1];
            const float e = __expf(y);
            vals[it] = e;
            local += e;
        } else {
            vals[it] = 0.0f;
        }
    }
    #pragma unroll
    for (int off = 32; off > 0; off >>= 1) local += __shfl_down(local, off, 64);
    if ((tid & 63) == 0) red[tid >> 6] = local;
    __syncthreads();
    const float total = red[0] + red[1] + red[2] + red[3];
    const float inv = 1.0f / total;
    #pragma unroll
    for (int it = 0; it < 5; ++it) {
        const int idx = tid + it * 256;
        if (idx < NCELL + 1) out[idx] = vals[it] * inv;
    }
}

extern "C" void kernel_launch(void* const* d_in, const int* in_sizes, int n_in,
                              void* d_out, int out_size, void* d_ws, size_t ws_size,
                              hipStream_t stream) {
    const float* inp    = (const float*)d_in[0];
    const float* w      = (const float*)d_in[1];
    const float* W_ih   = (const float*)d_in[2];
    const float* W_hh   = (const float*)d_in[3];
    const float* b_ih   = (const float*)d_in[4];
    const float* b_hh   = (const float*)d_in[5];
    const float* conv_w = (const float*)d_in[6];
    const float* conv_b = (const float*)d_in[7];
    float* out  = (float*)d_out;
    float* y_ws = (float*)d_ws;

    lstm_kernel<<<NCELL, 64, 0, stream>>>(inp, W_ih, W_hh, b_ih, b_hh, w,
                                          conv_w, conv_b, y_ws);
    softmax_kernel<<<1, 256, 0, stream>>>(y_ws, out);
}

// Round 7
// 344.573 us; speedup vs baseline: 1.0093x; 1.0093x over previous
//
#include <hip/hip_runtime.h>

#define TT 1024
#define KK 16
#define HH 20
#define NCELL 1024

__device__ __forceinline__ float fast_rcp(float x) {
    return __builtin_amdgcn_rcpf(x);
}
__device__ __forceinline__ float sigm(float x) {
    return fast_rcp(1.0f + __expf(-x));
}
__device__ __forceinline__ float tanh_fast(float x) {
    float e = __expf(2.0f * x);
    return 1.0f - 2.0f * fast_rcp(e + 1.0f);
}

__device__ __forceinline__ float bcast(float v, int srclane) {
    return __int_as_float(__builtin_amdgcn_readlane(__float_as_int(v), srclane));
}

struct F3 { float x, y, z; };

// ONE cell per wave: lanes 0..19 own hidden units (lane j = unit j's four gate
// rows, 80 weights held in VGPRs). Per-step h broadcast = 20 x v_readlane into
// SGPRs; gate FMAs consume h as the one-allowed-SGPR operand of v_fma_f32
// (no LDS pipe, no barriers).
//
// amdgpu_waves_per_eu(1, 1): BOTH bounds. R4-R6 showed VGPR_Count pinned at
// exactly 64 = the 8-waves/EU budget: min-only hints (launch_bounds(64,1),
// waves_per_eu(1)) leave the scheduler targeting MAX occupancy, and it sinks
// the loop-invariant weight loads back into the step loop to fit 64 VGPRs
// (~80 reloads/step on the critical path). max=1 is truthful (1024 blocks /
// 256 CUs = 1 wave/SIMD) and raises the pressure target to the full file.
__global__ __launch_bounds__(64)
__attribute__((amdgpu_waves_per_eu(1, 1)))
void lstm_kernel(
    const float* __restrict__ inp,    // [B][T][K][3]
    const float* __restrict__ W_ih,   // [K][80][3]
    const float* __restrict__ W_hh,   // [K][80][20]
    const float* __restrict__ b_ih,   // [K][80]
    const float* __restrict__ b_hh,   // [K][80]
    const float* __restrict__ w,      // [K*B+1]
    const float* __restrict__ conv_w, // [21]
    const float* __restrict__ conv_b, // [1]
    float* __restrict__ y_ws)         // [1024] pre-softmax y for rows 1..1024
{
    const int lane = threadIdx.x;
    const int cell = blockIdx.x;           // 0..1023
    const int k = cell >> 6;
    const int b = cell & 63;
    const int j = (lane < HH) ? lane : (HH - 1);  // lanes 20..63 shadow unit 19

    // Per-lane weights in registers (80 VGPRs of W_hh + 12 of W_ih + 4 bias).
    float W0[HH], W1[HH], W2[HH], W3[HH];
    float Wi0[3], Wi1[3], Wi2[3], Wi3[3];
    float bias0, bias1, bias2, bias3;
    {
        const int r0 = k * 80 + 0 * HH + j;
        const int r1 = k * 80 + 1 * HH + j;
        const int r2 = k * 80 + 2 * HH + j;
        const int r3 = k * 80 + 3 * HH + j;
        #pragma unroll
        for (int hh = 0; hh < HH; ++hh) {
            W0[hh] = W_hh[r0 * HH + hh];
            W1[hh] = W_hh[r1 * HH + hh];
            W2[hh] = W_hh[r2 * HH + hh];
            W3[hh] = W_hh[r3 * HH + hh];
        }
        #pragma unroll
        for (int i = 0; i < 3; ++i) {
            Wi0[i] = W_ih[r0 * 3 + i];
            Wi1[i] = W_ih[r1 * 3 + i];
            Wi2[i] = W_ih[r2 * 3 + i];
            Wi3[i] = W_ih[r3 * 3 + i];
        }
        bias0 = b_ih[r0] + b_hh[r0];
        bias1 = b_ih[r1] + b_hh[r1];
        bias2 = b_ih[r2] + b_hh[r2];
        bias3 = b_ih[r3] + b_hh[r3];
    }

    float h_own = 0.0f, c_own = 0.0f;

    // Wave-uniform input base: inp[((b*T + t)*K + k)*3], stride 48 floats/t.
    const float* xb = inp + (b * TT * KK + k) * 3;
    F3 p0{xb[0 * 48], xb[0 * 48 + 1], xb[0 * 48 + 2]};
    F3 p1{xb[1 * 48], xb[1 * 48 + 1], xb[1 * 48 + 2]};
    F3 p2{xb[2 * 48], xb[2 * 48 + 1], xb[2 * 48 + 2]};
    F3 p3{xb[3 * 48], xb[3 * 48 + 1], xb[3 * 48 + 2]};

    auto step = [&](F3& p, int t) {
        // 1) h broadcast: 20 readlanes -> SGPRs (no LDS pipe, no movs)
        float hs[HH];
        #pragma unroll
        for (int hh = 0; hh < HH; ++hh) hs[hh] = bcast(h_own, hh);

        const float x0 = p.x, x1 = p.y, x2 = p.z;
        // 2) refill p for step t+4 (uniform address; latency spans 4 steps)
        {
            int tn = t + 4; tn = (tn < TT) ? tn : (TT - 1);
            const float* q = xb + tn * (KK * 3);
            p.x = q[0]; p.y = q[1]; p.z = q[2];
        }
        // 3) x-projection + bias
        float a0 = bias0 + Wi0[0] * x0 + Wi0[1] * x1 + Wi0[2] * x2;
        float a1 = bias1 + Wi1[0] * x0 + Wi1[1] * x1 + Wi1[2] * x2;
        float a2 = bias2 + Wi2[0] * x0 + Wi2[1] * x1 + Wi2[2] * x2;
        float a3 = bias3 + Wi3[0] * x0 + Wi3[1] * x1 + Wi3[2] * x2;
        // 4) gate dots: v_fma with SGPR h operand, 4 independent chains
        #pragma unroll
        for (int hh = 0; hh < HH; ++hh) {
            const float hv = hs[hh];
            a0 += W0[hh] * hv;
            a1 += W1[hh] * hv;
            a2 += W2[hh] * hv;
            a3 += W3[hh] * hv;
        }
        // 5) nonlinearity + state update
        const float ig = sigm(a0);
        const float fg = sigm(a1);
        const float gt = tanh_fast(a2);
        const float og = sigm(a3);
        c_own = fg * c_own + ig * gt;
        h_own = og * tanh_fast(c_own);
    };

    for (int tb = 0; tb < TT; tb += 4) {
        step(p0, tb + 0);
        step(p1, tb + 1);
        step(p2, tb + 2);
        step(p3, tb + 3);
    }

    // Epilogue: final h via readlane (uniform), y = tanh(feat . conv_w + conv_b)
    float acc = conv_b[0];
    #pragma unroll
    for (int hh = 0; hh < HH; ++hh) acc += conv_w[hh] * bcast(h_own, hh);
    acc += conv_w[HH] * w[1 + cell];
    if (lane == 0) y_ws[cell] = tanh_fast(acc);
}

// Softmax over [1, y_0 .. y_1023] -> out[1025]
__global__ __launch_bounds__(256) void softmax_kernel(
    const float* __restrict__ y_ws, float* __restrict__ out)
{
    __shared__ float red[4];
    const int tid = threadIdx.x;
    float vals[5];
    float local = 0.0f;
    #pragma unroll
    for (int it = 0; it < 5; ++it) {
        const int idx = tid + it * 256;
        if (idx < NCELL + 1) {
            const float y = (idx == 0) ? 1.0f : y_ws[idx - 1];
            const float e = __expf(y);
            vals[it] = e;
            local += e;
        } else {
            vals[it] = 0.0f;
        }
    }
    #pragma unroll
    for (int off = 32; off > 0; off >>= 1) local += __shfl_down(local, off, 64);
    if ((tid & 63) == 0) red[tid >> 6] = local;
    __syncthreads();
    const float total = red[0] + red[1] + red[2] + red[3];
    const float inv = 1.0f / total;
    #pragma unroll
    for (int it = 0; it < 5; ++it) {
        const int idx = tid + it * 256;
        if (idx < NCELL + 1) out[idx] = vals[it] * inv;
    }
}

extern "C" void kernel_launch(void* const* d_in, const int* in_sizes, int n_in,
                              void* d_out, int out_size, void* d_ws, size_t ws_size,
                              hipStream_t stream) {
    const float* inp    = (const float*)d_in[0];
    const float* w      = (const float*)d_in[1];
    const float* W_ih   = (const float*)d_in[2];
    const float* W_hh   = (const float*)d_in[3];
    const float* b_ih   = (const float*)d_in[4];
    const float* b_hh   = (const float*)d_in[5];
    const float* conv_w = (const float*)d_in[6];
    const float* conv_b = (const float*)d_in[7];
    float* out  = (float*)d_out;
    float* y_ws = (float*)d_ws;

    lstm_kernel<<<NCELL, 64, 0, stream>>>(inp, W_ih, W_hh, b_ih, b_hh, w,
                                          conv_w, conv_b, y_ws);
    softmax_kernel<<<1, 256, 0, stream>>>(y_ws, out);
}

// Round 8
// 274.699 us; speedup vs baseline: 1.2661x; 1.2544x over previous
//
#include <hip/hip_runtime.h>

#define TT 1024
#define KK 16
#define HH 20
#define NCELL 1024

typedef float f32x2 __attribute__((ext_vector_type(2)));

// d = w * h + c, with h as a wave-uniform SGPR pair (VOP3P allows one scalar
// source). Pair assembly from readlane results is SALU s_movs — off the VALU
// critical path — vs R4's 20 v_movs/step.
__device__ __forceinline__ f32x2 pk_fma_sv(f32x2 w_v, f32x2 h_s, f32x2 c_v) {
    f32x2 d;
    asm("v_pk_fma_f32 %0, %1, %2, %3" : "=v"(d) : "v"(w_v), "s"(h_s), "v"(c_v));
    return d;
}

__device__ __forceinline__ float fast_rcp(float x) {
    return __builtin_amdgcn_rcpf(x);
}
__device__ __forceinline__ float sigm(float x) {
    return fast_rcp(1.0f + __expf(-x));
}
__device__ __forceinline__ float tanh_fast(float x) {
    float e = __expf(2.0f * x);
    return 1.0f - 2.0f * fast_rcp(e + 1.0f);
}

__device__ __forceinline__ float bcast(float v, int srclane) {
    return __int_as_float(__builtin_amdgcn_readlane(__float_as_int(v), srclane));
}

struct F3 { float x, y, z; };

// ONE cell per wave: lanes 0..19 own hidden units (lane j = unit j's four
// gate rows in VGPRs). Per-step h broadcast = 20 v_readlane -> SGPRs, consumed
// directly as the scalar operand of v_pk_fma_f32 (no LDS pipe, no barriers,
// no pack movs). 40 pk_fma replaces 80 scalar fma (R4 proved -50us).
// waves_per_eu(1,1): truthful (1024 blocks / 256 CU = 1 wave/SIMD) and gives
// the allocator the full register file (R7: VGPR 64->132).
__global__ __launch_bounds__(64)
__attribute__((amdgpu_waves_per_eu(1, 1)))
void lstm_kernel(
    const float* __restrict__ inp,    // [B][T][K][3]
    const float* __restrict__ W_ih,   // [K][80][3]
    const float* __restrict__ W_hh,   // [K][80][20]
    const float* __restrict__ b_ih,   // [K][80]
    const float* __restrict__ b_hh,   // [K][80]
    const float* __restrict__ w,      // [K*B+1]
    const float* __restrict__ conv_w, // [21]
    const float* __restrict__ conv_b, // [1]
    float* __restrict__ y_ws)         // [1024] pre-softmax y for rows 1..1024
{
    const int lane = threadIdx.x;
    const int cell = blockIdx.x;           // 0..1023
    const int k = cell >> 6;
    const int b = cell & 63;
    const int j = (lane < HH) ? lane : (HH - 1);  // lanes 20..63 shadow unit 19

    // Per-lane weights in registers, packed (even hh, odd hh) for v_pk_fma.
    f32x2 Wp0[10], Wp1[10], Wp2[10], Wp3[10];
    float Wi0[3], Wi1[3], Wi2[3], Wi3[3];
    float bias0, bias1, bias2, bias3;
    {
        const int r0 = k * 80 + 0 * HH + j;
        const int r1 = k * 80 + 1 * HH + j;
        const int r2 = k * 80 + 2 * HH + j;
        const int r3 = k * 80 + 3 * HH + j;
        #pragma unroll
        for (int m = 0; m < 10; ++m) {
            Wp0[m] = f32x2{W_hh[r0 * HH + 2 * m], W_hh[r0 * HH + 2 * m + 1]};
            Wp1[m] = f32x2{W_hh[r1 * HH + 2 * m], W_hh[r1 * HH + 2 * m + 1]};
            Wp2[m] = f32x2{W_hh[r2 * HH + 2 * m], W_hh[r2 * HH + 2 * m + 1]};
            Wp3[m] = f32x2{W_hh[r3 * HH + 2 * m], W_hh[r3 * HH + 2 * m + 1]};
        }
        #pragma unroll
        for (int i = 0; i < 3; ++i) {
            Wi0[i] = W_ih[r0 * 3 + i];
            Wi1[i] = W_ih[r1 * 3 + i];
            Wi2[i] = W_ih[r2 * 3 + i];
            Wi3[i] = W_ih[r3 * 3 + i];
        }
        bias0 = b_ih[r0] + b_hh[r0];
        bias1 = b_ih[r1] + b_hh[r1];
        bias2 = b_ih[r2] + b_hh[r2];
        bias3 = b_ih[r3] + b_hh[r3];
    }

    float h_own = 0.0f, c_own = 0.0f;

    // Wave-uniform input base: inp[((b*T + t)*K + k)*3], stride 48 floats/t.
    const float* xb = inp + (b * TT * KK + k) * 3;
    F3 p0{xb[0 * 48], xb[0 * 48 + 1], xb[0 * 48 + 2]};
    F3 p1{xb[1 * 48], xb[1 * 48 + 1], xb[1 * 48 + 2]};
    F3 p2{xb[2 * 48], xb[2 * 48 + 1], xb[2 * 48 + 2]};
    F3 p3{xb[3 * 48], xb[3 * 48 + 1], xb[3 * 48 + 2]};

    auto step = [&](F3& p, int t) {
        // 1) h broadcast: 20 readlanes -> uniform scalars (SGPRs), then
        //    uniform pairs consumed straight from SGPRs by pk_fma.
        float hs[HH];
        #pragma unroll
        for (int hh = 0; hh < HH; ++hh) hs[hh] = bcast(h_own, hh);
        f32x2 hp[10];
        #pragma unroll
        for (int m = 0; m < 10; ++m) hp[m] = f32x2{hs[2 * m], hs[2 * m + 1]};

        const float x0 = p.x, x1 = p.y, x2 = p.z;
        // 2) refill p for step t+4 (uniform address; latency spans 4 steps)
        {
            int tn = t + 4; tn = (tn < TT) ? tn : (TT - 1);
            const float* q = xb + tn * (KK * 3);
            p.x = q[0]; p.y = q[1]; p.z = q[2];
        }
        // 3) x-projection + bias (off the h critical path)
        const float e0 = bias0 + Wi0[0] * x0 + Wi0[1] * x1 + Wi0[2] * x2;
        const float e1 = bias1 + Wi1[0] * x0 + Wi1[1] * x1 + Wi1[2] * x2;
        const float e2 = bias2 + Wi2[0] * x0 + Wi2[1] * x1 + Wi2[2] * x2;
        const float e3 = bias3 + Wi3[0] * x0 + Wi3[1] * x1 + Wi3[2] * x2;
        // 4) packed gate dots, h from SGPR pairs
        f32x2 a0{e0, 0.f}, a1{e1, 0.f}, a2{e2, 0.f}, a3{e3, 0.f};
        #pragma unroll
        for (int m = 0; m < 10; ++m) {
            a0 = pk_fma_sv(Wp0[m], hp[m], a0);
            a1 = pk_fma_sv(Wp1[m], hp[m], a1);
            a2 = pk_fma_sv(Wp2[m], hp[m], a2);
            a3 = pk_fma_sv(Wp3[m], hp[m], a3);
        }
        const float gi = a0.x + a0.y;
        const float gf = a1.x + a1.y;
        const float gz = a2.x + a2.y;
        const float go = a3.x + a3.y;
        // 5) nonlinearity + state update
        const float ig = sigm(gi);
        const float fg = sigm(gf);
        const float gt = tanh_fast(gz);
        const float og = sigm(go);
        c_own = fg * c_own + ig * gt;
        h_own = og * tanh_fast(c_own);
    };

    for (int tb = 0; tb < TT; tb += 4) {
        step(p0, tb + 0);
        step(p1, tb + 1);
        step(p2, tb + 2);
        step(p3, tb + 3);
    }

    // Epilogue: final h via readlane (uniform), y = tanh(feat . conv_w + conv_b)
    float acc = conv_b[0];
    #pragma unroll
    for (int hh = 0; hh < HH; ++hh) acc += conv_w[hh] * bcast(h_own, hh);
    acc += conv_w[HH] * w[1 + cell];
    if (lane == 0) y_ws[cell] = tanh_fast(acc);
}

// Softmax over [1, y_0 .. y_1023] -> out[1025]
__global__ __launch_bounds__(256) void softmax_kernel(
    const float* __restrict__ y_ws, float* __restrict__ out)
{
    __shared__ float red[4];
    const int tid = threadIdx.x;
    float vals[5];
    float local = 0.0f;
    #pragma unroll
    for (int it = 0; it < 5; ++it) {
        const int idx = tid + it * 256;
        if (idx < NCELL + 1) {
            const float y = (idx == 0) ? 1.0f : y_ws[idx - 1];
            const float e = __expf(y);
            vals[it] = e;
            local += e;
        } else {
            vals[it] = 0.0f;
        }
    }
    #pragma unroll
    for (int off = 32; off > 0; off >>= 1) local += __shfl_down(local, off, 64);
    if ((tid & 63) == 0) red[tid >> 6] = local;
    __syncthreads();
    const float total = red[0] + red[1] + red[2] + red[3];
    const float inv = 1.0f / total;
    #pragma unroll
    for (int it = 0; it < 5; ++it) {
        const int idx = tid + it * 256;
        if (idx < NCELL + 1) out[idx] = vals[it] * inv;
    }
}

extern "C" void kernel_launch(void* const* d_in, const int* in_sizes, int n_in,
                              void* d_out, int out_size, void* d_ws, size_t ws_size,
                              hipStream_t stream) {
    const float* inp    = (const float*)d_in[0];
    const float* w      = (const float*)d_in[1];
    const float* W_ih   = (const float*)d_in[2];
    const float* W_hh   = (const float*)d_in[3];
    const float* b_ih   = (const float*)d_in[4];
    const float* b_hh   = (const float*)d_in[5];
    const float* conv_w = (const float*)d_in[6];
    const float* conv_b = (const float*)d_in[7];
    float* out  = (float*)d_out;
    float* y_ws = (float*)d_ws;

    lstm_kernel<<<NCELL, 64, 0, stream>>>(inp, W_ih, W_hh, b_ih, b_hh, w,
                                          conv_w, conv_b, y_ws);
    softmax_kernel<<<1, 256, 0, stream>>>(y_ws, out);
}

// Round 9
// 199.134 us; speedup vs baseline: 1.7465x; 1.3795x over previous
//
#include <hip/hip_runtime.h>

#define TT 1024
#define KK 16
#define HH 20
#define NCELL 1024

typedef float f32x2 __attribute__((ext_vector_type(2)));

// d = w * h + c, with h as a wave-uniform SGPR pair (VOP3P allows one scalar
// source); pair assembly from readlane results is SALU, off the VALU path.
__device__ __forceinline__ f32x2 pk_fma_sv(f32x2 w_v, f32x2 h_s, f32x2 c_v) {
    f32x2 d;
    asm("v_pk_fma_f32 %0, %1, %2, %3" : "=v"(d) : "v"(w_v), "s"(h_s), "v"(c_v));
    return d;
}

__device__ __forceinline__ float fast_rcp(float x) {
    return __builtin_amdgcn_rcpf(x);
}
__device__ __forceinline__ float sigm(float x) {
    return fast_rcp(1.0f + __expf(-x));
}
__device__ __forceinline__ float tanh_fast(float x) {
    float e = __expf(2.0f * x);
    return 1.0f - 2.0f * fast_rcp(e + 1.0f);
}

__device__ __forceinline__ float bcast(float v, int srclane) {
    return __int_as_float(__builtin_amdgcn_readlane(__float_as_int(v), srclane));
}

// v_permlane32_swap_b32 a, b: a.hi <- b.lo, b.lo <- a.hi (gfx950).
// With a = b = v this yields a = v's low-half value in ALL lanes and
// b = v's high-half value in ALL lanes — one instr per full-wave half-bcast.
__device__ __forceinline__ void half_bcast(float v, float& from_lo, float& from_hi) {
    float a = v, b = v;
    asm("v_permlane32_swap_b32 %0, %1" : "+v"(a), "+v"(b));
    from_lo = a; from_hi = b;
}

struct F3 { float x, y, z; };

// ONE cell per wave, gates split across wave halves:
//   lanes 0..31  (jj=lane&31, unit j=min(jj,19)): gate rows i (j), f (20+j)
//   lanes 32..63: gate rows g (40+j), o (60+j)
// Each lane: 2 gate rows = 20 pk_fma/step (R8 had 40). Recombine with two
// v_permlane32_swap_b32. A-gate activation unified across halves via
// tanh(x) = 2*sigm(2x)-1 (per-half scale/bias, no divergence): 3 exp chains
// per step instead of 5. h broadcast stays 20 x v_readlane -> SGPR pairs.
// waves_per_eu(1,1): truthful (1024 blocks / 256 CU = 1 wave/SIMD); gives the
// allocator the full register file (R4-R7 showed min-only hints pin 64 VGPRs).
__global__ __launch_bounds__(64)
__attribute__((amdgpu_waves_per_eu(1, 1)))
void lstm_kernel(
    const float* __restrict__ inp,    // [B][T][K][3]
    const float* __restrict__ W_ih,   // [K][80][3]
    const float* __restrict__ W_hh,   // [K][80][20]
    const float* __restrict__ b_ih,   // [K][80]
    const float* __restrict__ b_hh,   // [K][80]
    const float* __restrict__ w,      // [K*B+1]
    const float* __restrict__ conv_w, // [21]
    const float* __restrict__ conv_b, // [1]
    float* __restrict__ y_ws)         // [1024] pre-softmax y for rows 1..1024
{
    const int lane = threadIdx.x;
    const int cell = blockIdx.x;           // 0..1023
    const int k = cell >> 6;
    const int b = cell & 63;
    const int half = lane >> 5;            // 0: gates i,f   1: gates g,o
    const int jj = lane & 31;
    const int j = (jj < HH) ? jj : (HH - 1);  // lanes with jj>=20 shadow unit 19

    // Per-lane weights: gate A = (half?g:i), gate B = (half?o:f).
    f32x2 WpA[10], WpB[10];
    float WiA[3], WiB[3];
    float biasA, biasB;
    {
        const int rA = k * 80 + (half * 2) * HH + j;   // i (row j) or g (40+j)
        const int rB = rA + HH;                        // f (20+j) or o (60+j)
        #pragma unroll
        for (int m = 0; m < 10; ++m) {
            WpA[m] = f32x2{W_hh[rA * HH + 2 * m], W_hh[rA * HH + 2 * m + 1]};
            WpB[m] = f32x2{W_hh[rB * HH + 2 * m], W_hh[rB * HH + 2 * m + 1]};
        }
        #pragma unroll
        for (int i = 0; i < 3; ++i) {
            WiA[i] = W_ih[rA * 3 + i];
            WiB[i] = W_ih[rB * 3 + i];
        }
        biasA = b_ih[rA] + b_hh[rA];
        biasB = b_ih[rB] + b_hh[rB];
    }
    // A-gate activation constants: half0 sigma(x); half1 tanh(x)=2*sigma(2x)-1.
    const float scA = half ? 2.0f : 1.0f;
    const float mA  = half ? 2.0f : 1.0f;
    const float bA  = half ? -1.0f : 0.0f;

    float h_own = 0.0f, c_own = 0.0f;

    // Wave-uniform input base: inp[((b*T + t)*K + k)*3], stride 48 floats/t.
    const float* xb = inp + (b * TT * KK + k) * 3;
    F3 p0{xb[0 * 48], xb[0 * 48 + 1], xb[0 * 48 + 2]};
    F3 p1{xb[1 * 48], xb[1 * 48 + 1], xb[1 * 48 + 2]};
    F3 p2{xb[2 * 48], xb[2 * 48 + 1], xb[2 * 48 + 2]};
    F3 p3{xb[3 * 48], xb[3 * 48 + 1], xb[3 * 48 + 2]};

    auto step = [&](F3& p, int t) {
        // 1) h broadcast: 20 readlanes -> SGPR pairs for pk_fma.
        float hs[HH];
        #pragma unroll
        for (int hh = 0; hh < HH; ++hh) hs[hh] = bcast(h_own, hh);
        f32x2 hp[10];
        #pragma unroll
        for (int m = 0; m < 10; ++m) hp[m] = f32x2{hs[2 * m], hs[2 * m + 1]};

        const float x0 = p.x, x1 = p.y, x2 = p.z;
        // 2) refill p for step t+4 (uniform address; latency spans 4 steps)
        {
            int tn = t + 4; tn = (tn < TT) ? tn : (TT - 1);
            const float* q = xb + tn * (KK * 3);
            p.x = q[0]; p.y = q[1]; p.z = q[2];
        }
        // 3) x-projection + bias (off the h critical path)
        const float eA = biasA + WiA[0] * x0 + WiA[1] * x1 + WiA[2] * x2;
        const float eB = biasB + WiB[0] * x0 + WiB[1] * x1 + WiB[2] * x2;
        // 4) packed gate dots (2 rows/lane), h from SGPR pairs
        f32x2 aA{eA, 0.f}, aB{eB, 0.f};
        #pragma unroll
        for (int m = 0; m < 10; ++m) {
            aA = pk_fma_sv(WpA[m], hp[m], aA);
            aB = pk_fma_sv(WpB[m], hp[m], aB);
        }
        const float gA = aA.x + aA.y;   // half0: i-pre   half1: g-pre
        const float gB = aB.x + aB.y;   // half0: f-pre   half1: o-pre
        // 5) unified activation (no divergence): actA = sigm or tanh, actB = sigm
        const float uA = sigm(gA * scA);
        const float actA = uA * mA + bA;
        const float actB = sigm(gB);
        // 6) cross-half exchange: every lane gets sI, tG, sF, sO for unit jj
        float sI, tG, sF, sO;
        half_bcast(actA, sI, tG);
        half_bcast(actB, sF, sO);
        // 7) state update (redundant in both halves; h_own valid in lanes 0..19)
        c_own = sF * c_own + sI * tG;
        h_own = sO * tanh_fast(c_own);
    };

    for (int tb = 0; tb < TT; tb += 4) {
        step(p0, tb + 0);
        step(p1, tb + 1);
        step(p2, tb + 2);
        step(p3, tb + 3);
    }

    // Epilogue: final h via readlane (uniform), y = tanh(feat . conv_w + conv_b)
    float acc = conv_b[0];
    #pragma unroll
    for (int hh = 0; hh < HH; ++hh) acc += conv_w[hh] * bcast(h_own, hh);
    acc += conv_w[HH] * w[1 + cell];
    if (lane == 0) y_ws[cell] = tanh_fast(acc);
}

// Softmax over [1, y_0 .. y_1023] -> out[1025]
__global__ __launch_bounds__(256) void softmax_kernel(
    const float* __restrict__ y_ws, float* __restrict__ out)
{
    __shared__ float red[4];
    const int tid = threadIdx.x;
    float vals[5];
    float local = 0.0f;
    #pragma unroll
    for (int it = 0; it < 5; ++it) {
        const int idx = tid + it * 256;
        if (idx < NCELL + 1) {
            const float y = (idx == 0) ? 1.0f : y_ws[idx - 1];
            const float e = __expf(y);
            vals[it] = e;
            local += e;
        } else {
            vals[it] = 0.0f;
        }
    }
    #pragma unroll
    for (int off = 32; off > 0; off >>= 1) local += __shfl_down(local, off, 64);
    if ((tid & 63) == 0) red[tid >> 6] = local;
    __syncthreads();
    const float total = red[0] + red[1] + red[2] + red[3];
    const float inv = 1.0f / total;
    #pragma unroll
    for (int it = 0; it < 5; ++it) {
        const int idx = tid + it * 256;
        if (idx < NCELL + 1) out[idx] = vals[it] * inv;
    }
}

extern "C" void kernel_launch(void* const* d_in, const int* in_sizes, int n_in,
                              void* d_out, int out_size, void* d_ws, size_t ws_size,
                              hipStream_t stream) {
    const float* inp    = (const float*)d_in[0];
    const float* w      = (const float*)d_in[1];
    const float* W_ih   = (const float*)d_in[2];
    const float* W_hh   = (const float*)d_in[3];
    const float* b_ih   = (const float*)d_in[4];
    const float* b_hh   = (const float*)d_in[5];
    const float* conv_w = (const float*)d_in[6];
    const float* conv_b = (const float*)d_in[7];
    float* out  = (float*)d_out;
    float* y_ws = (float*)d_ws;

    lstm_kernel<<<NCELL, 64, 0, stream>>>(inp, W_ih, W_hh, b_ih, b_hh, w,
                                          conv_w, conv_b, y_ws);
    softmax_kernel<<<1, 256, 0, stream>>>(y_ws, out);
}

// Round 10
// 185.330 us; speedup vs baseline: 1.8766x; 1.0745x over previous
//
#include <hip/hip_runtime.h>

#define TT 1024
#define KK 16
#define HH 20
#define NCELL 1024

typedef _Float16 f16;
typedef f16 f16x2 __attribute__((ext_vector_type(2)));

#define LOG2E 1.4426950408889634f

__device__ __forceinline__ float fdot2(f16x2 a, f16x2 b, float c) {
    // v_dot2_f32_f16: a.x*b.x + a.y*b.y + c, f32 accumulate, 2 MACs / 2 cy.
    return __builtin_amdgcn_fdot2(a, b, c, false);
}

__device__ __forceinline__ float fast_rcp(float x) {
    return __builtin_amdgcn_rcpf(x);
}

// sigmoid in exp2 domain: x already scaled by log2e -> rcp(1 + 2^-x), no muls.
__device__ __forceinline__ float sigm2(float x2) {
    return fast_rcp(1.0f + __builtin_amdgcn_exp2f(-x2));
}

// tanh of a TRUE-domain value (one mul to enter exp2 domain).
__device__ __forceinline__ float tanh_fast(float x) {
    float e = __builtin_amdgcn_exp2f(x * (2.0f * LOG2E));
    return 1.0f - 2.0f * fast_rcp(e + 1.0f);
}

__device__ __forceinline__ float bcast(float v, int srclane) {
    return __int_as_float(__builtin_amdgcn_readlane(__float_as_int(v), srclane));
}
__device__ __forceinline__ unsigned bcast_u(unsigned v, int srclane) {
    return (unsigned)__builtin_amdgcn_readlane((int)v, srclane);
}

// v_permlane32_swap_b32 a,b with a=b=v: a = v's low-half value in ALL lanes,
// b = v's high-half value in ALL lanes.
__device__ __forceinline__ void half_bcast(float v, float& from_lo, float& from_hi) {
    float a = v, b = v;
    asm("v_permlane32_swap_b32 %0, %1" : "+v"(a), "+v"(b));
    from_lo = a; from_hi = b;
}

struct F3 { float x, y, z; };

// ONE cell per wave, gates split across wave halves:
//   lanes 0..31  (unit j=min(lane&31,19)): gate rows i (j),    f (20+j)
//   lanes 32..63:                          gate rows g (40+j), o (60+j)
// Recurrent weights in f16, PRE-SCALED by log2e (x2 for the g row) so every
// activation is rcp(1+exp2(-x)) directly. Gate dots via v_dot2_f32_f16
// (2 MACs / 2 cy, f32 accum) in two 5-deep chains per row. h broadcast:
// own-h -> f16, neighbor pair via DPP quad_perm(xor1) + shl_or, then 10
// readlanes of packed f16x2 (uniform -> scalar operand of dot2).
// waves_per_eu(1,1): truthful (1024 blocks / 256 CU = 1 wave/SIMD); gives the
// allocator the full register file (R4-R7: min-only hints pin 64 VGPRs).
__global__ __launch_bounds__(64)
__attribute__((amdgpu_waves_per_eu(1, 1)))
void lstm_kernel(
    const float* __restrict__ inp,    // [B][T][K][3]
    const float* __restrict__ W_ih,   // [K][80][3]
    const float* __restrict__ W_hh,   // [K][80][20]
    const float* __restrict__ b_ih,   // [K][80]
    const float* __restrict__ b_hh,   // [K][80]
    const float* __restrict__ w,      // [K*B+1]
    const float* __restrict__ conv_w, // [21]
    const float* __restrict__ conv_b, // [1]
    float* __restrict__ y_ws)         // [1024] pre-softmax y for rows 1..1024
{
    const int lane = threadIdx.x;
    const int cell = blockIdx.x;           // 0..1023
    const int k = cell >> 6;
    const int b = cell & 63;
    const int half = lane >> 5;            // 0: rows i,f   1: rows g,o
    const int jj = lane & 31;
    const int j = (jj < HH) ? jj : (HH - 1);

    // Per-lane weights: row A = (half?g:i), row B = (half?o:f), f16 pre-scaled.
    f16x2 WpA[10], WpB[10];
    float WiA[3], WiB[3];
    float biasA, biasB;
    {
        const int rA = k * 80 + (half * 2) * HH + j;
        const int rB = rA + HH;
        const float scaleA = LOG2E * (half ? 2.0f : 1.0f);  // g-row: sigma(2x)
        const float scaleB = LOG2E;
        #pragma unroll
        for (int m = 0; m < 10; ++m) {
            WpA[m] = f16x2{(f16)(W_hh[rA * HH + 2 * m] * scaleA),
                           (f16)(W_hh[rA * HH + 2 * m + 1] * scaleA)};
            WpB[m] = f16x2{(f16)(W_hh[rB * HH + 2 * m] * scaleB),
                           (f16)(W_hh[rB * HH + 2 * m + 1] * scaleB)};
        }
        #pragma unroll
        for (int i = 0; i < 3; ++i) {
            WiA[i] = W_ih[rA * 3 + i] * scaleA;
            WiB[i] = W_ih[rB * 3 + i] * scaleB;
        }
        biasA = (b_ih[rA] + b_hh[rA]) * scaleA;
        biasB = (b_ih[rB] + b_hh[rB]) * scaleB;
    }
    // A-row post-activation affine: half0 identity; half1 tanh = 2*sigma(2x)-1.
    const float mA = half ? 2.0f : 1.0f;
    const float bA = half ? -1.0f : 0.0f;

    float h_own = 0.0f, c_own = 0.0f;

    // Wave-uniform input base: inp[((b*T + t)*K + k)*3], stride 48 floats/t.
    const float* xb = inp + (b * TT * KK + k) * 3;
    F3 p0{xb[0 * 48], xb[0 * 48 + 1], xb[0 * 48 + 2]};
    F3 p1{xb[1 * 48], xb[1 * 48 + 1], xb[1 * 48 + 2]};
    F3 p2{xb[2 * 48], xb[2 * 48 + 1], xb[2 * 48 + 2]};
    F3 p3{xb[3 * 48], xb[3 * 48 + 1], xb[3 * 48 + 2]};

    auto step = [&](F3& p, int t) {
        // 1) h -> f16; pair with neighbor (DPP quad_perm xor1); 10 readlanes
        //    of packed f16x2 -> wave-uniform scalar operands for dot2.
        unsigned hb = (unsigned)__builtin_bit_cast(unsigned short, (f16)h_own);
        unsigned nb = (unsigned)__builtin_amdgcn_mov_dpp((int)hb, 0xB1, 0xF, 0xF, true);
        const unsigned packed = hb | (nb << 16);  // even lane 2m: (h[2m], h[2m+1])
        f16x2 hp[10];
        #pragma unroll
        for (int m = 0; m < 10; ++m)
            hp[m] = __builtin_bit_cast(f16x2, bcast_u(packed, 2 * m));

        const float x0 = p.x, x1 = p.y, x2 = p.z;
        // 2) refill p for step t+4 (uniform address; latency spans 4 steps)
        {
            int tn = t + 4; tn = (tn < TT) ? tn : (TT - 1);
            const float* q = xb + tn * (KK * 3);
            p.x = q[0]; p.y = q[1]; p.z = q[2];
        }
        // 3) x-projection + bias (f32, off the h critical path)
        const float eA = biasA + WiA[0] * x0 + WiA[1] * x1 + WiA[2] * x2;
        const float eB = biasB + WiB[0] * x0 + WiB[1] * x1 + WiB[2] * x2;
        // 4) gate dots: 10 dot2 per row, split into two 5-deep chains
        float pA0 = eA, pA1 = 0.f, pB0 = eB, pB1 = 0.f;
        #pragma unroll
        for (int m = 0; m < 5; ++m) {
            pA0 = fdot2(WpA[m], hp[m], pA0);
            pB0 = fdot2(WpB[m], hp[m], pB0);
            pA1 = fdot2(WpA[m + 5], hp[m + 5], pA1);
            pB1 = fdot2(WpB[m + 5], hp[m + 5], pB1);
        }
        const float gA = pA0 + pA1;     // half0: i-pre   half1: g-pre (scaled)
        const float gB = pB0 + pB1;     // half0: f-pre   half1: o-pre (scaled)
        // 5) activations (exp2 domain, no pre-muls)
        const float uA = sigm2(gA);
        const float actA = uA * mA + bA;       // sigma(i) or tanh(g)
        const float actB = sigm2(gB);          // sigma(f) or sigma(o)
        // 6) cross-half exchange: all lanes get sI, tG, sF, sO for unit jj
        float sI, tG, sF, sO;
        half_bcast(actA, sI, tG);
        half_bcast(actB, sF, sO);
        // 7) state update (h_own valid in lanes 0..19, shadowed in 32..51)
        c_own = sF * c_own + sI * tG;
        h_own = sO * tanh_fast(c_own);
    };

    for (int tb = 0; tb < TT; tb += 4) {
        step(p0, tb + 0);
        step(p1, tb + 1);
        step(p2, tb + 2);
        step(p3, tb + 3);
    }

    // Epilogue: final h via readlane (f32), y = tanh(feat . conv_w + conv_b)
    float acc = conv_b[0];
    #pragma unroll
    for (int hh = 0; hh < HH; ++hh) acc += conv_w[hh] * bcast(h_own, hh);
    acc += conv_w[HH] * w[1 + cell];
    if (lane == 0) y_ws[cell] = tanh_fast(acc);
}

// Softmax over [1, y_0 .. y_1023] -> out[1025]
__global__ __launch_bounds__(256) void softmax_kernel(
    const float* __restrict__ y_ws, float* __restrict__ out)
{
    __shared__ float red[4];
    const int tid = threadIdx.x;
    float vals[5];
    float local = 0.0f;
    #pragma unroll
    for (int it = 0; it < 5; ++it) {
        const int idx = tid + it * 256;
        if (idx < NCELL + 1) {
            const float y = (idx == 0) ? 1.0f : y_ws[idx - 1];
            const float e = __expf(y);
            vals[it] = e;
            local += e;
        } else {
            vals[it] = 0.0f;
        }
    }
    #pragma unroll
    for (int off = 32; off > 0; off >>= 1) local += __shfl_down(local, off, 64);
    if ((tid & 63) == 0) red[tid >> 6] = local;
    __syncthreads();
    const float total = red[0] + red[1] + red[2] + red[3];
    const float inv = 1.0f / total;
    #pragma unroll
    for (int it = 0; it < 5; ++it) {
        const int idx = tid + it * 256;
        if (idx < NCELL + 1) out[idx] = vals[it] * inv;
    }
}

extern "C" void kernel_launch(void* const* d_in, const int* in_sizes, int n_in,
                              void* d_out, int out_size, void* d_ws, size_t ws_size,
                              hipStream_t stream) {
    const float* inp    = (const float*)d_in[0];
    const float* w      = (const float*)d_in[1];
    const float* W_ih   = (const float*)d_in[2];
    const float* W_hh   = (const float*)d_in[3];
    const float* b_ih   = (const float*)d_in[4];
    const float* b_hh   = (const float*)d_in[5];
    const float* conv_w = (const float*)d_in[6];
    const float* conv_b = (const float*)d_in[7];
    float* out  = (float*)d_out;
    float* y_ws = (float*)d_ws;

    lstm_kernel<<<NCELL, 64, 0, stream>>>(inp, W_ih, W_hh, b_ih, b_hh, w,
                                          conv_w, conv_b, y_ws);
    softmax_kernel<<<1, 256, 0, stream>>>(y_ws, out);
}